// Round 1
// baseline (9498.678 us; speedup 1.0000x reference)
//
#include <hip/hip_runtime.h>
#include <stdint.h>

#define TT 128
#define BB 128
#define OBSD 512
#define HID 1024

typedef short bf16x8 __attribute__((ext_vector_type(8)));
typedef float f32x4 __attribute__((ext_vector_type(4)));

__device__ __forceinline__ unsigned short bf_rne(float x){
  unsigned u = __builtin_bit_cast(unsigned, x);
  unsigned r = u + 0x7fffu + ((u >> 16) & 1u);
  return (unsigned short)(r >> 16);
}
__device__ __forceinline__ float bf2f(unsigned short b){
  unsigned u = ((unsigned)b) << 16;
  return __builtin_bit_cast(float, u);
}
__device__ __forceinline__ f32x4 mfma16(bf16x8 a, bf16x8 b, f32x4 c){
  return __builtin_amdgcn_mfma_f32_16x16x32_bf16(a, b, c, 0, 0, 0);
}

// ---- prep: world_state f32 -> bf16 (row-major, k contiguous) ----
__global__ void k_ws_to_bf(const float* __restrict__ src, unsigned short* __restrict__ dst, int n4){
  int i = blockIdx.x * blockDim.x + threadIdx.x;
  if (i < n4){
    float4 v = *reinterpret_cast<const float4*>(src + (size_t)i * 4);
    ushort4 o;
    o.x = bf_rne(v.x); o.y = bf_rne(v.y); o.z = bf_rne(v.z); o.w = bf_rne(v.w);
    *reinterpret_cast<ushort4*>(dst + (size_t)i * 4) = o;
  }
}

// ---- prep: build transposed bf16 B matrices dst[c][kk], tiled transpose ----
// mode 0: W_emb (512x1024) -> dst[1024][512]           (plain bf16)
// mode 1: [Wi; Wh_hi; Wh_lo; Wh_hi] -> dst[3072][4096] (src stride 3072)
// mode 2: [W1_hi; W1_lo; W1_hi] -> dst[1024][3072]     (src stride 1024)
__global__ void k_prep_bt(int mode, const float* __restrict__ s0, const float* __restrict__ s1,
                          unsigned short* __restrict__ dst, int C, int KD){
  __shared__ unsigned short sm[64][65];
  int k0 = blockIdx.x * 64, c0 = blockIdx.y * 64;
  for (int it = 0; it < 16; ++it){
    int idx = it * 256 + threadIdx.x;
    int kr = idx >> 6, cc = idx & 63;
    int kk = k0 + kr, c = c0 + cc;
    unsigned short o;
    if (mode == 0){
      o = bf_rne(s0[(size_t)kk * 1024 + c]);
    } else if (mode == 1){
      if (kk < 1024){ o = bf_rne(s0[(size_t)kk * 3072 + c]); }
      else if (kk < 2048){ o = bf_rne(s1[(size_t)(kk - 1024) * 3072 + c]); }
      else if (kk < 3072){ float w = s1[(size_t)(kk - 2048) * 3072 + c];
                           unsigned short h = bf_rne(w); o = bf_rne(w - bf2f(h)); }
      else { o = bf_rne(s1[(size_t)(kk - 3072) * 3072 + c]); }
    } else {
      if (kk < 1024){ o = bf_rne(s0[(size_t)kk * 1024 + c]); }
      else if (kk < 2048){ float w = s0[(size_t)(kk - 1024) * 1024 + c];
                           unsigned short h = bf_rne(w); o = bf_rne(w - bf2f(h)); }
      else { o = bf_rne(s0[(size_t)(kk - 2048) * 1024 + c]); }
    }
    sm[kr][cc] = o;
  }
  __syncthreads();
  for (int it = 0; it < 16; ++it){
    int idx = it * 256 + threadIdx.x;
    int cr = idx >> 6, kc = idx & 63;
    dst[(size_t)(c0 + cr) * KD + (k0 + kc)] = sm[kc][cr];
  }
}

// ---- prep: initial hidden state, masked by dones[0], f32 + hi/lo split ----
__global__ void k_h_init(const float* __restrict__ hidden, const int* __restrict__ dones,
                         float* __restrict__ hf, unsigned short* __restrict__ hhi,
                         unsigned short* __restrict__ hlo){
  int i = blockIdx.x * 256 + threadIdx.x;   // b*1024 + j
  int b = i >> 10;
  float h = dones[b] ? 0.f : hidden[i];
  hf[i] = h;
  unsigned short hi = bf_rne(h);
  hhi[i] = hi;
  hlo[i] = bf_rne(h - bf2f(hi));
}

// ---- emb = relu(ws_bf @ W_emb + b_emb), output bf16 ----
__global__ __launch_bounds__(256)
void k_emb(const unsigned short* __restrict__ A, const unsigned short* __restrict__ Bt,
           const float* __restrict__ bias, unsigned short* __restrict__ outb){
  int w = threadIdx.x >> 6, lane = threadIdx.x & 63;
  int wm = w >> 1, wn = w & 1;
  int Mb = blockIdx.x * 64, Nb = blockIdx.y * 64;
  int la = lane & 15, lk = (lane >> 4) * 8;
  f32x4 acc[2][2];
  for (int a = 0; a < 2; ++a) for (int bq = 0; bq < 2; ++bq) acc[a][bq] = (f32x4){0.f,0.f,0.f,0.f};
  const int K = OBSD;
  for (int k = 0; k < K; k += 32){
    bf16x8 a0 = *reinterpret_cast<const bf16x8*>(A + (size_t)(Mb + wm*32 + la) * K + k + lk);
    bf16x8 a1 = *reinterpret_cast<const bf16x8*>(A + (size_t)(Mb + wm*32 + 16 + la) * K + k + lk);
    bf16x8 b0 = *reinterpret_cast<const bf16x8*>(Bt + (size_t)(Nb + wn*32 + la) * K + k + lk);
    bf16x8 b1 = *reinterpret_cast<const bf16x8*>(Bt + (size_t)(Nb + wn*32 + 16 + la) * K + k + lk);
    acc[0][0] = mfma16(a0, b0, acc[0][0]);
    acc[0][1] = mfma16(a0, b1, acc[0][1]);
    acc[1][0] = mfma16(a1, b0, acc[1][0]);
    acc[1][1] = mfma16(a1, b1, acc[1][1]);
  }
  for (int mi = 0; mi < 2; ++mi) for (int ni = 0; ni < 2; ++ni){
    int col = Nb + wn*32 + ni*16 + la;
    float bb = bias[col];
    for (int i = 0; i < 4; ++i){
      int row = Mb + wm*32 + mi*16 + (lane >> 4)*4 + i;
      float v = acc[mi][ni][i] + bb;
      v = v > 0.f ? v : 0.f;
      outb[(size_t)row * HID + col] = bf_rne(v);
    }
  }
}

// ---- per-step GRU: [emb_t | h_hi | h_hi | h_lo] @ Bt_cat, gates, write state ----
__global__ __launch_bounds__(256)
void k_scan(int t, const unsigned short* __restrict__ emb_bf,
            const unsigned short* __restrict__ Bt,
            const float* __restrict__ bi, const float* __restrict__ bhn,
            const int* __restrict__ dones,
            const float* __restrict__ hf_src, const unsigned short* __restrict__ hhi_src,
            const unsigned short* __restrict__ hlo_src,
            float* __restrict__ hf_dst, unsigned short* __restrict__ hhi_dst,
            unsigned short* __restrict__ hlo_dst,
            unsigned short* __restrict__ yhi, unsigned short* __restrict__ ylo,
            float* __restrict__ hout){
  int w = threadIdx.x >> 6, lane = threadIdx.x & 63;
  int cs = blockIdx.x & 63, mb = blockIdx.x >> 6;
  int la = lane & 15, lk = (lane >> 4) * 8;
  int row = mb*64 + w*16 + la;
  f32x4 accr = (f32x4){0.f,0.f,0.f,0.f};
  f32x4 accz = accr, accxn = accr, acchn = accr;
  const unsigned short* Br = Bt + (size_t)(cs*16 + la) * 4096;
  const unsigned short* Bz = Bt + (size_t)(1024 + cs*16 + la) * 4096;
  const unsigned short* Bn = Bt + (size_t)(2048 + cs*16 + la) * 4096;
  const unsigned short* Ae  = emb_bf + ((size_t)t * BB + row) * HID;
  const unsigned short* Ahi = hhi_src + (size_t)row * HID;
  const unsigned short* Alo = hlo_src + (size_t)row * HID;
  // region 1: emb @ Wi  (xn separate accumulator)
  #pragma unroll 4
  for (int k = 0; k < 1024; k += 32){
    bf16x8 a  = *reinterpret_cast<const bf16x8*>(Ae + k + lk);
    bf16x8 br = *reinterpret_cast<const bf16x8*>(Br + k + lk);
    bf16x8 bz = *reinterpret_cast<const bf16x8*>(Bz + k + lk);
    bf16x8 bn = *reinterpret_cast<const bf16x8*>(Bn + k + lk);
    accr = mfma16(a, br, accr); accz = mfma16(a, bz, accz); accxn = mfma16(a, bn, accxn);
  }
  // region 2: h_hi @ Wh_hi
  #pragma unroll 4
  for (int k = 0; k < 1024; k += 32){
    bf16x8 a  = *reinterpret_cast<const bf16x8*>(Ahi + k + lk);
    bf16x8 br = *reinterpret_cast<const bf16x8*>(Br + 1024 + k + lk);
    bf16x8 bz = *reinterpret_cast<const bf16x8*>(Bz + 1024 + k + lk);
    bf16x8 bn = *reinterpret_cast<const bf16x8*>(Bn + 1024 + k + lk);
    accr = mfma16(a, br, accr); accz = mfma16(a, bz, accz); acchn = mfma16(a, bn, acchn);
  }
  // region 3: h_hi @ Wh_lo
  #pragma unroll 4
  for (int k = 0; k < 1024; k += 32){
    bf16x8 a  = *reinterpret_cast<const bf16x8*>(Ahi + k + lk);
    bf16x8 br = *reinterpret_cast<const bf16x8*>(Br + 2048 + k + lk);
    bf16x8 bz = *reinterpret_cast<const bf16x8*>(Bz + 2048 + k + lk);
    bf16x8 bn = *reinterpret_cast<const bf16x8*>(Bn + 2048 + k + lk);
    accr = mfma16(a, br, accr); accz = mfma16(a, bz, accz); acchn = mfma16(a, bn, acchn);
  }
  // region 4: h_lo @ Wh_hi
  #pragma unroll 4
  for (int k = 0; k < 1024; k += 32){
    bf16x8 a  = *reinterpret_cast<const bf16x8*>(Alo + k + lk);
    bf16x8 br = *reinterpret_cast<const bf16x8*>(Br + 3072 + k + lk);
    bf16x8 bz = *reinterpret_cast<const bf16x8*>(Bz + 3072 + k + lk);
    bf16x8 bn = *reinterpret_cast<const bf16x8*>(Bn + 3072 + k + lk);
    accr = mfma16(a, br, accr); accz = mfma16(a, bz, accz); acchn = mfma16(a, bn, acchn);
  }
  int j = cs*16 + la;
  float bir = bi[j], biz = bi[HID + j], bin = bi[2*HID + j], bh = bhn[j];
  for (int i = 0; i < 4; ++i){
    int b = mb*64 + w*16 + (lane >> 4)*4 + i;
    float r = 1.f / (1.f + expf(-(accr[i] + bir)));
    float z = 1.f / (1.f + expf(-(accz[i] + biz)));
    float n = tanhf(accxn[i] + bin + r * (acchn[i] + bh));
    size_t hix = (size_t)b * HID + j;
    float hold = hf_src[hix];
    float hn = (1.f - z) * n + z * hold;
    size_t yi = ((size_t)t * BB + b) * HID + j;
    unsigned short h16 = bf_rne(hn);
    yhi[yi] = h16;
    ylo[yi] = bf_rne(hn - bf2f(h16));
    if (t == TT - 1) hout[hix] = hn;
    float he = hn;
    if (t + 1 < TT && dones[(t + 1) * BB + b]) he = 0.f;
    hf_dst[hix] = he;
    unsigned short e16 = bf_rne(he);
    hhi_dst[hix] = e16;
    hlo_dst[hix] = bf_rne(he - bf2f(e16));
  }
}

// ---- critic = relu([y_hi|y_hi|y_lo] @ [W1hi;W1lo;W1hi] + b1), output f32 ----
__global__ __launch_bounds__(256)
void k_critic(const unsigned short* __restrict__ Yhi, const unsigned short* __restrict__ Ylo,
              const unsigned short* __restrict__ Bt, const float* __restrict__ bias,
              float* __restrict__ outf){
  int w = threadIdx.x >> 6, lane = threadIdx.x & 63;
  int wm = w >> 1, wn = w & 1;
  int Mb = blockIdx.x * 64, Nb = blockIdx.y * 64;
  int la = lane & 15, lk = (lane >> 4) * 8;
  f32x4 acc[2][2];
  for (int a = 0; a < 2; ++a) for (int bq = 0; bq < 2; ++bq) acc[a][bq] = (f32x4){0.f,0.f,0.f,0.f};
  const unsigned short* A0 = Yhi + (size_t)(Mb + wm*32 + la) * HID;
  const unsigned short* A1 = Yhi + (size_t)(Mb + wm*32 + 16 + la) * HID;
  const unsigned short* C0 = Ylo + (size_t)(Mb + wm*32 + la) * HID;
  const unsigned short* C1 = Ylo + (size_t)(Mb + wm*32 + 16 + la) * HID;
  const unsigned short* B0 = Bt + (size_t)(Nb + wn*32 + la) * 3072;
  const unsigned short* B1 = Bt + (size_t)(Nb + wn*32 + 16 + la) * 3072;
  for (int reg = 0; reg < 3; ++reg){
    const unsigned short* a0 = (reg < 2) ? A0 : C0;
    const unsigned short* a1 = (reg < 2) ? A1 : C1;
    int koff = reg * 1024;
    #pragma unroll 4
    for (int k = 0; k < 1024; k += 32){
      bf16x8 fa0 = *reinterpret_cast<const bf16x8*>(a0 + k + lk);
      bf16x8 fa1 = *reinterpret_cast<const bf16x8*>(a1 + k + lk);
      bf16x8 fb0 = *reinterpret_cast<const bf16x8*>(B0 + koff + k + lk);
      bf16x8 fb1 = *reinterpret_cast<const bf16x8*>(B1 + koff + k + lk);
      acc[0][0] = mfma16(fa0, fb0, acc[0][0]);
      acc[0][1] = mfma16(fa0, fb1, acc[0][1]);
      acc[1][0] = mfma16(fa1, fb0, acc[1][0]);
      acc[1][1] = mfma16(fa1, fb1, acc[1][1]);
    }
  }
  for (int mi = 0; mi < 2; ++mi) for (int ni = 0; ni < 2; ++ni){
    int col = Nb + wn*32 + ni*16 + la;
    float bb = bias[col];
    for (int i = 0; i < 4; ++i){
      int row = Mb + wm*32 + mi*16 + (lane >> 4)*4 + i;
      float v = acc[mi][ni][i] + bb;
      outf[(size_t)row * HID + col] = v > 0.f ? v : 0.f;
    }
  }
}

// ---- value[m] = critic[m,:] . W2 + b2 ----
__global__ __launch_bounds__(256)
void k_value(const float* __restrict__ critic, const float* __restrict__ W2,
             const float* __restrict__ b2, float* __restrict__ outv){
  int w = threadIdx.x >> 6, lane = threadIdx.x & 63;
  int m = blockIdx.x * 4 + w;
  const float* rowp = critic + (size_t)m * HID;
  float s = 0.f;
  #pragma unroll
  for (int i = 0; i < 16; ++i) s += rowp[lane + i*64] * W2[lane + i*64];
  for (int off = 32; off > 0; off >>= 1) s += __shfl_down(s, off);
  if (lane == 0) outv[m] = s + b2[0];
}

extern "C" void kernel_launch(void* const* d_in, const int* in_sizes, int n_in,
                              void* d_out, int out_size, void* d_ws, size_t ws_size,
                              hipStream_t stream){
  const float* hidden = (const float*)d_in[0];
  const float* world  = (const float*)d_in[1];
  const int*   dones  = (const int*)d_in[2];
  const float* W_emb  = (const float*)d_in[3];
  const float* b_emb  = (const float*)d_in[4];
  const float* Wi     = (const float*)d_in[5];
  const float* bi     = (const float*)d_in[6];
  const float* Wh     = (const float*)d_in[7];
  const float* bhn    = (const float*)d_in[8];
  const float* W1     = (const float*)d_in[9];
  const float* b1     = (const float*)d_in[10];
  const float* W2     = (const float*)d_in[11];
  const float* b2     = (const float*)d_in[12];
  float* out = (float*)d_out;

  char* p = (char*)d_ws;
  auto alloc = [&](size_t bytes) -> char* {
    char* r = p; p += (bytes + 255) & ~(size_t)255; return r;
  };
  unsigned short* ws_bf  = (unsigned short*)alloc((size_t)TT*BB*OBSD*2);   // 16 MB
  unsigned short* wembt  = (unsigned short*)alloc((size_t)HID*OBSD*2);     // 1 MB
  unsigned short* emb_bf = (unsigned short*)alloc((size_t)TT*BB*HID*2);    // 33.5 MB
  unsigned short* btcat  = (unsigned short*)alloc((size_t)3072*4096*2);    // 25 MB
  unsigned short* w1t    = (unsigned short*)alloc((size_t)HID*3072*2);     // 6.3 MB
  unsigned short* yhi    = (unsigned short*)alloc((size_t)TT*BB*HID*2);    // 33.5 MB
  unsigned short* ylo    = (unsigned short*)alloc((size_t)TT*BB*HID*2);    // 33.5 MB
  float*          critic = (float*)alloc((size_t)TT*BB*HID*4);             // 67 MB
  float*          hf0    = (float*)alloc((size_t)BB*HID*4);
  float*          hf1    = (float*)alloc((size_t)BB*HID*4);
  unsigned short* hhi0   = (unsigned short*)alloc((size_t)BB*HID*2);
  unsigned short* hhi1   = (unsigned short*)alloc((size_t)BB*HID*2);
  unsigned short* hlo0   = (unsigned short*)alloc((size_t)BB*HID*2);
  unsigned short* hlo1   = (unsigned short*)alloc((size_t)BB*HID*2);
  if ((size_t)(p - (char*)d_ws) > ws_size) return;  // workspace too small

  // preps
  k_ws_to_bf<<<(TT*BB*OBSD/4 + 255)/256, 256, 0, stream>>>(world, ws_bf, TT*BB*OBSD/4);
  k_prep_bt<<<dim3(OBSD/64, HID/64), 256, 0, stream>>>(0, W_emb, nullptr, wembt, HID, OBSD);
  k_prep_bt<<<dim3(4096/64, 3072/64), 256, 0, stream>>>(1, Wi, Wh, btcat, 3072, 4096);
  k_prep_bt<<<dim3(3072/64, HID/64), 256, 0, stream>>>(2, W1, nullptr, w1t, HID, 3072);
  k_h_init<<<(BB*HID)/256, 256, 0, stream>>>(hidden, dones, hf0, hhi0, hlo0);

  // embedding GEMM
  k_emb<<<dim3(TT*BB/64, HID/64), 256, 0, stream>>>(ws_bf, wembt, b_emb, emb_bf);

  // sequential GRU scan, one launch per step
  float* hf[2] = {hf0, hf1};
  unsigned short* hhi[2] = {hhi0, hhi1};
  unsigned short* hlo[2] = {hlo0, hlo1};
  for (int t = 0; t < TT; ++t){
    int s = t & 1;
    k_scan<<<128, 256, 0, stream>>>(t, emb_bf, btcat, bi, bhn, dones,
                                    hf[s], hhi[s], hlo[s],
                                    hf[s^1], hhi[s^1], hlo[s^1],
                                    yhi, ylo, out);
  }

  // critic head + value
  k_critic<<<dim3(TT*BB/64, HID/64), 256, 0, stream>>>(yhi, ylo, w1t, b1, critic);
  k_value<<<TT*BB/4, 256, 0, stream>>>(critic, W2, b2, out + (size_t)BB*HID);
}

// Round 2
// 3321.046 us; speedup vs baseline: 2.8601x; 2.8601x over previous
//
#include <hip/hip_runtime.h>
#include <stdint.h>

#define TT 128
#define BB 128
#define OBSD 512
#define HID 1024

typedef short bf16x8 __attribute__((ext_vector_type(8)));
typedef float f32x4 __attribute__((ext_vector_type(4)));

__device__ __forceinline__ unsigned short bf_rne(float x){
  unsigned u = __builtin_bit_cast(unsigned, x);
  unsigned r = u + 0x7fffu + ((u >> 16) & 1u);
  return (unsigned short)(r >> 16);
}
__device__ __forceinline__ float bf2f(unsigned short b){
  unsigned u = ((unsigned)b) << 16;
  return __builtin_bit_cast(float, u);
}
__device__ __forceinline__ f32x4 mfma16(bf16x8 a, bf16x8 b, f32x4 c){
  return __builtin_amdgcn_mfma_f32_16x16x32_bf16(a, b, c, 0, 0, 0);
}

// ---- prep: world_state f32 -> bf16 ----
__global__ void k_ws_to_bf(const float* __restrict__ src, unsigned short* __restrict__ dst, int n4){
  int i = blockIdx.x * blockDim.x + threadIdx.x;
  if (i < n4){
    float4 v = *reinterpret_cast<const float4*>(src + (size_t)i * 4);
    ushort4 o;
    o.x = bf_rne(v.x); o.y = bf_rne(v.y); o.z = bf_rne(v.z); o.w = bf_rne(v.w);
    *reinterpret_cast<ushort4*>(dst + (size_t)i * 4) = o;
  }
}

// ---- prep: transposed bf16 B matrices dst[c][kk] ----
// mode 0: W_emb (512x1024) -> dst[1024][512]
// mode 1: [Wi; Wh_hi; Wh_lo; Wh_hi] -> dst[3072][4096] (src strides 3072)
// mode 2: [W1_hi; W1_lo; W1_hi] -> dst[1024][3072]     (src stride 1024)
__global__ void k_prep_bt(int mode, const float* __restrict__ s0, const float* __restrict__ s1,
                          unsigned short* __restrict__ dst, int C, int KD){
  __shared__ unsigned short sm[64][65];
  int k0 = blockIdx.x * 64, c0 = blockIdx.y * 64;
  for (int it = 0; it < 16; ++it){
    int idx = it * 256 + threadIdx.x;
    int kr = idx >> 6, cc = idx & 63;
    int kk = k0 + kr, c = c0 + cc;
    unsigned short o;
    if (mode == 0){
      o = bf_rne(s0[(size_t)kk * 1024 + c]);
    } else if (mode == 1){
      if (kk < 1024){ o = bf_rne(s0[(size_t)kk * 3072 + c]); }
      else if (kk < 2048){ o = bf_rne(s1[(size_t)(kk - 1024) * 3072 + c]); }
      else if (kk < 3072){ float w = s1[(size_t)(kk - 2048) * 3072 + c];
                           unsigned short h = bf_rne(w); o = bf_rne(w - bf2f(h)); }
      else { o = bf_rne(s1[(size_t)(kk - 3072) * 3072 + c]); }
    } else {
      if (kk < 1024){ o = bf_rne(s0[(size_t)kk * 1024 + c]); }
      else if (kk < 2048){ float w = s0[(size_t)(kk - 1024) * 1024 + c];
                           unsigned short h = bf_rne(w); o = bf_rne(w - bf2f(h)); }
      else { o = bf_rne(s0[(size_t)(kk - 2048) * 1024 + c]); }
    }
    sm[kr][cc] = o;
  }
  __syncthreads();
  for (int it = 0; it < 16; ++it){
    int idx = it * 256 + threadIdx.x;
    int cr = idx >> 6, kc = idx & 63;
    dst[(size_t)(c0 + cr) * KD + (k0 + kc)] = sm[kc][cr];
  }
}

// ---- prep: initial hidden state (masked by dones[0]) as hi/lo bf16 ----
__global__ void k_h_init(const float* __restrict__ hidden, const int* __restrict__ dones,
                         unsigned short* __restrict__ hhi, unsigned short* __restrict__ hlo){
  int i = blockIdx.x * 256 + threadIdx.x;
  int b = i >> 10;
  float h = dones[b] ? 0.f : hidden[i];
  unsigned short hi16 = bf_rne(h);
  hhi[i] = hi16;
  hlo[i] = bf_rne(h - bf2f(hi16));
}

// ---- emb = relu(ws_bf @ W_emb + b_emb), 128x128 tile, XCD swizzle ----
__global__ __launch_bounds__(256)
void k_emb(const unsigned short* __restrict__ A, const unsigned short* __restrict__ Bt,
           const float* __restrict__ bias, unsigned short* __restrict__ outb){
  int w = threadIdx.x >> 6, lane = threadIdx.x & 63;
  int wm = w >> 1, wn = w & 1;
  int bid = blockIdx.x;                       // 1024 blocks = 128 Mb x 8 Nb
  int vid = (bid & 7) * 128 + (bid >> 3);     // XCD-chunked, Nb fast
  int Mb = (vid >> 3) * 128, Nb = (vid & 7) * 128;
  int la = lane & 15, lk = (lane >> 4) * 8;
  f32x4 acc[4][4] = {};
  const unsigned short* Ap[4]; const unsigned short* Bp[4];
  for (int i = 0; i < 4; ++i){
    Ap[i] = A + (size_t)(Mb + wm*64 + i*16 + la) * OBSD;
    Bp[i] = Bt + (size_t)(Nb + wn*64 + i*16 + la) * OBSD;
  }
  for (int k = 0; k < OBSD; k += 32){
    bf16x8 af[4], bfr[4];
    for (int i = 0; i < 4; ++i){
      af[i]  = *reinterpret_cast<const bf16x8*>(Ap[i] + k + lk);
      bfr[i] = *reinterpret_cast<const bf16x8*>(Bp[i] + k + lk);
    }
    for (int mi = 0; mi < 4; ++mi)
      for (int ni = 0; ni < 4; ++ni)
        acc[mi][ni] = mfma16(af[mi], bfr[ni], acc[mi][ni]);
  }
  for (int mi = 0; mi < 4; ++mi) for (int ni = 0; ni < 4; ++ni){
    int col = Nb + wn*64 + ni*16 + la;
    float bb = bias[col];
    for (int i = 0; i < 4; ++i){
      int row = Mb + wm*64 + mi*16 + (lane >> 4)*4 + i;
      float v = acc[mi][ni][i] + bb;
      outb[(size_t)row * HID + col] = bf_rne(v > 0.f ? v : 0.f);
    }
  }
}

// ---- per-step GRU: 256 blocks x 256 thr; wave = K-region; LDS reduce ----
__global__ __launch_bounds__(256)
void k_scan(int t, const unsigned short* __restrict__ emb_bf,
            const unsigned short* __restrict__ Bt,
            const float* __restrict__ bi, const float* __restrict__ bhn,
            const int* __restrict__ dones,
            const unsigned short* __restrict__ hhi_src, const unsigned short* __restrict__ hlo_src,
            unsigned short* __restrict__ hhi_dst, unsigned short* __restrict__ hlo_dst,
            unsigned short* __restrict__ yhi, unsigned short* __restrict__ ylo,
            float* __restrict__ hout){
  __shared__ float red[4][3][2][64][5];
  int w = threadIdx.x >> 6, lane = threadIdx.x & 63;
  int bid = blockIdx.x;                      // 256 blocks
  int vid = (bid & 7) * 32 + (bid >> 3);     // XCD-chunked: one XCD owns 8 cs x 4 rg
  int cs = vid >> 2, rg = vid & 3;           // cs in [0,64), rg in [0,4)
  int la = lane & 15, lk = (lane >> 4) * 8;
  int rowbase = rg * 32;
  const unsigned short* Abase =
      (w == 0) ? emb_bf + (size_t)t * BB * HID
    : (w == 3) ? hlo_src : hhi_src;
  const unsigned short* A0 = Abase + (size_t)(rowbase + la) * HID;
  const unsigned short* A1 = Abase + (size_t)(rowbase + 16 + la) * HID;
  int koff = w * 1024;
  const unsigned short* Br = Bt + (size_t)(cs*16 + la) * 4096 + koff;
  const unsigned short* Bz = Bt + (size_t)(1024 + cs*16 + la) * 4096 + koff;
  const unsigned short* Bn = Bt + (size_t)(2048 + cs*16 + la) * 4096 + koff;
  f32x4 ar0 = {}, ar1 = {}, az0 = {}, az1 = {}, an0 = {}, an1 = {};
  #pragma unroll 4
  for (int k = 0; k < 1024; k += 32){
    bf16x8 a0 = *reinterpret_cast<const bf16x8*>(A0 + k + lk);
    bf16x8 a1 = *reinterpret_cast<const bf16x8*>(A1 + k + lk);
    bf16x8 br = *reinterpret_cast<const bf16x8*>(Br + k + lk);
    bf16x8 bz = *reinterpret_cast<const bf16x8*>(Bz + k + lk);
    bf16x8 bn = *reinterpret_cast<const bf16x8*>(Bn + k + lk);
    ar0 = mfma16(a0, br, ar0); ar1 = mfma16(a1, br, ar1);
    az0 = mfma16(a0, bz, az0); az1 = mfma16(a1, bz, az1);
    an0 = mfma16(a0, bn, an0); an1 = mfma16(a1, bn, an1);
  }
  for (int i = 0; i < 4; ++i){
    red[w][0][0][lane][i] = ar0[i]; red[w][0][1][lane][i] = ar1[i];
    red[w][1][0][lane][i] = az0[i]; red[w][1][1][lane][i] = az1[i];
    red[w][2][0][lane][i] = an0[i]; red[w][2][1][lane][i] = an1[i];
  }
  __syncthreads();
  int lane2 = threadIdx.x & 63, i2 = threadIdx.x >> 6;
  int j = cs*16 + (lane2 & 15);
  float bir = bi[j], biz = bi[HID + j], bin = bi[2*HID + j], bh = bhn[j];
  #pragma unroll
  for (int f = 0; f < 2; ++f){
    int row = rg*32 + f*16 + ((lane2 >> 4) << 2) + i2;
    float xr = red[0][0][f][lane2][i2];
    float xz = red[0][1][f][lane2][i2];
    float xn = red[0][2][f][lane2][i2];
    float hr = red[1][0][f][lane2][i2] + red[2][0][f][lane2][i2] + red[3][0][f][lane2][i2];
    float hz = red[1][1][f][lane2][i2] + red[2][1][f][lane2][i2] + red[3][1][f][lane2][i2];
    float hn = red[1][2][f][lane2][i2] + red[2][2][f][lane2][i2] + red[3][2][f][lane2][i2];
    float r = 1.f / (1.f + expf(-(xr + bir + hr)));
    float z = 1.f / (1.f + expf(-(xz + biz + hz)));
    float n = tanhf(xn + bin + r * (hn + bh));
    size_t hix = (size_t)row * HID + j;
    float hold = bf2f(hhi_src[hix]) + bf2f(hlo_src[hix]);
    float hnew = (1.f - z) * n + z * hold;
    size_t yi = ((size_t)t * BB + row) * HID + j;
    unsigned short h16 = bf_rne(hnew);
    yhi[yi] = h16;
    ylo[yi] = bf_rne(hnew - bf2f(h16));
    if (t == TT - 1) hout[hix] = hnew;
    float he = hnew;
    if (t + 1 < TT && dones[(t + 1) * BB + row]) he = 0.f;
    unsigned short e16 = bf_rne(he);
    hhi_dst[hix] = e16;
    hlo_dst[hix] = bf_rne(he - bf2f(e16));
  }
}

// ---- critic fused with value partials: 128x128 tile, XCD swizzle ----
__global__ __launch_bounds__(256)
void k_critic(const unsigned short* __restrict__ Yhi, const unsigned short* __restrict__ Ylo,
              const unsigned short* __restrict__ Bt, const float* __restrict__ b1,
              const float* __restrict__ W2, float* __restrict__ vpart){
  int w = threadIdx.x >> 6, lane = threadIdx.x & 63;
  int wm = w >> 1, wn = w & 1;
  int bid = blockIdx.x;                       // 1024 blocks = 128 Mb x 8 Nb
  int vid = (bid & 7) * 128 + (bid >> 3);
  int Mb = (vid >> 3) * 128, Nb = (vid & 7) * 128;
  int la = lane & 15, lk = (lane >> 4) * 8;
  f32x4 acc[4][4] = {};
  const unsigned short* Bp[4];
  for (int i = 0; i < 4; ++i) Bp[i] = Bt + (size_t)(Nb + wn*64 + i*16 + la) * 3072;
  for (int reg = 0; reg < 3; ++reg){
    const unsigned short* Asrc = (reg < 2) ? Yhi : Ylo;
    const unsigned short* Ap[4];
    for (int i = 0; i < 4; ++i) Ap[i] = Asrc + (size_t)(Mb + wm*64 + i*16 + la) * HID;
    int koff = reg * 1024;
    #pragma unroll 2
    for (int k = 0; k < 1024; k += 32){
      bf16x8 af[4], bfr[4];
      for (int i = 0; i < 4; ++i){
        af[i]  = *reinterpret_cast<const bf16x8*>(Ap[i] + k + lk);
        bfr[i] = *reinterpret_cast<const bf16x8*>(Bp[i] + koff + k + lk);
      }
      for (int mi = 0; mi < 4; ++mi)
        for (int ni = 0; ni < 4; ++ni)
          acc[mi][ni] = mfma16(af[mi], bfr[ni], acc[mi][ni]);
    }
  }
  // relu + dot with W2 -> per-row partial over this block's 128 cols
  __shared__ float vs[2][64][2];
  float p[4][4];
  for (int mi = 0; mi < 4; ++mi) for (int i = 0; i < 4; ++i) p[mi][i] = 0.f;
  for (int ni = 0; ni < 4; ++ni){
    int col = Nb + wn*64 + ni*16 + la;
    float bb = b1[col], w2 = W2[col];
    for (int mi = 0; mi < 4; ++mi)
      for (int i = 0; i < 4; ++i){
        float c = acc[mi][ni][i] + bb;
        p[mi][i] += (c > 0.f ? c : 0.f) * w2;
      }
  }
  for (int mi = 0; mi < 4; ++mi) for (int i = 0; i < 4; ++i){
    float s = p[mi][i];
    s += __shfl_xor(s, 1); s += __shfl_xor(s, 2);
    s += __shfl_xor(s, 4); s += __shfl_xor(s, 8);
    p[mi][i] = s;                 // valid at la == 0 lanes
  }
  if (la == 0){
    int q = lane >> 4;
    for (int mi = 0; mi < 4; ++mi)
      for (int i = 0; i < 4; ++i)
        vs[wm][mi*16 + q*4 + i][wn] = p[mi][i];
  }
  __syncthreads();
  if (threadIdx.x < 128){
    int rw = threadIdx.x;
    float s = vs[rw >> 6][rw & 63][0] + vs[rw >> 6][rw & 63][1];
    vpart[(size_t)(Nb >> 7) * (TT*BB) + Mb + rw] = s;
  }
}

// ---- value[m] = sum_nb vpart[nb][m] + b2 ----
__global__ void k_vreduce(const float* __restrict__ vpart, const float* __restrict__ b2,
                          float* __restrict__ outv){
  int m = blockIdx.x * 256 + threadIdx.x;
  float s = b2[0];
  for (int nb = 0; nb < 8; ++nb) s += vpart[(size_t)nb * (TT*BB) + m];
  outv[m] = s;
}

extern "C" void kernel_launch(void* const* d_in, const int* in_sizes, int n_in,
                              void* d_out, int out_size, void* d_ws, size_t ws_size,
                              hipStream_t stream){
  const float* hidden = (const float*)d_in[0];
  const float* world  = (const float*)d_in[1];
  const int*   dones  = (const int*)d_in[2];
  const float* W_emb  = (const float*)d_in[3];
  const float* b_emb  = (const float*)d_in[4];
  const float* Wi     = (const float*)d_in[5];
  const float* bi     = (const float*)d_in[6];
  const float* Wh     = (const float*)d_in[7];
  const float* bhn    = (const float*)d_in[8];
  const float* W1     = (const float*)d_in[9];
  const float* b1     = (const float*)d_in[10];
  const float* W2     = (const float*)d_in[11];
  const float* b2     = (const float*)d_in[12];
  float* out = (float*)d_out;

  char* p = (char*)d_ws;
  auto alloc = [&](size_t bytes) -> char* {
    char* r = p; p += (bytes + 255) & ~(size_t)255; return r;
  };
  unsigned short* ws_bf  = (unsigned short*)alloc((size_t)TT*BB*OBSD*2);   // 16 MB
  unsigned short* wembt  = (unsigned short*)alloc((size_t)HID*OBSD*2);     // 1 MB
  unsigned short* emb_bf = (unsigned short*)alloc((size_t)TT*BB*HID*2);    // 33.5 MB
  unsigned short* btcat  = (unsigned short*)alloc((size_t)3072*4096*2);    // 25 MB
  unsigned short* w1t    = (unsigned short*)alloc((size_t)HID*3072*2);     // 6.3 MB
  unsigned short* yhi    = (unsigned short*)alloc((size_t)TT*BB*HID*2);    // 33.5 MB
  unsigned short* ylo    = (unsigned short*)alloc((size_t)TT*BB*HID*2);    // 33.5 MB
  unsigned short* hhi0   = (unsigned short*)alloc((size_t)BB*HID*2);
  unsigned short* hhi1   = (unsigned short*)alloc((size_t)BB*HID*2);
  unsigned short* hlo0   = (unsigned short*)alloc((size_t)BB*HID*2);
  unsigned short* hlo1   = (unsigned short*)alloc((size_t)BB*HID*2);
  float*          vpart  = (float*)alloc((size_t)8*TT*BB*4);               // 0.5 MB
  if ((size_t)(p - (char*)d_ws) > ws_size) return;  // workspace too small

  // preps
  k_ws_to_bf<<<(TT*BB*OBSD/4 + 255)/256, 256, 0, stream>>>(world, ws_bf, TT*BB*OBSD/4);
  k_prep_bt<<<dim3(OBSD/64, HID/64), 256, 0, stream>>>(0, W_emb, nullptr, wembt, HID, OBSD);
  k_prep_bt<<<dim3(4096/64, 3072/64), 256, 0, stream>>>(1, Wi, Wh, btcat, 3072, 4096);
  k_prep_bt<<<dim3(3072/64, HID/64), 256, 0, stream>>>(2, W1, nullptr, w1t, HID, 3072);
  k_h_init<<<(BB*HID)/256, 256, 0, stream>>>(hidden, dones, hhi0, hlo0);

  // embedding GEMM
  k_emb<<<1024, 256, 0, stream>>>(ws_bf, wembt, b_emb, emb_bf);

  // sequential GRU scan
  unsigned short* hhi[2] = {hhi0, hhi1};
  unsigned short* hlo[2] = {hlo0, hlo1};
  for (int t = 0; t < TT; ++t){
    int s = t & 1;
    k_scan<<<256, 256, 0, stream>>>(t, emb_bf, btcat, bi, bhn, dones,
                                    hhi[s], hlo[s], hhi[s^1], hlo[s^1],
                                    yhi, ylo, out);
  }

  // critic head fused with value partials + final reduce
  k_critic<<<1024, 256, 0, stream>>>(yhi, ylo, w1t, b1, W2, vpart);
  k_vreduce<<<TT*BB/256, 256, 0, stream>>>(vpart, b2, out + (size_t)BB*HID);
}